// Round 3
// baseline (4436.689 us; speedup 1.0000x reference)
//
#include <hip/hip_runtime.h>
#include <hip/hip_bf16.h>

#define N_CELLS  200000
#define N_FACES  400000
#define N_POINTS 200000
#define E_CF     800000
#define E_FP     800000
#define E_PP     1200000

__device__ __forceinline__ float bf2f(unsigned short u) {
    union { unsigned int i; float f; } v; v.i = ((unsigned int)u) << 16; return v.f;
}
__device__ __forceinline__ unsigned short f2bf(float f) {
    __hip_bfloat16 h = __float2bfloat16(f);
    return *reinterpret_cast<unsigned short*>(&h);
}

// ---------------- init: buf[r][j] = b[j] ----------------
__global__ __launch_bounds__(256) void k_init_bias(float* __restrict__ buf,
                                                   const float* __restrict__ b,
                                                   int total4, int colmask4) {
    int t = blockIdx.x * 256 + threadIdx.x;
    if (t >= total4) return;
    float4 v = ((const float4*)b)[t & colmask4];
    ((float4*)buf)[t] = v;
}

// ---------------- stage A: h_c = x_centers @ W_cf (bf16) ----------------
__global__ __launch_bounds__(256) void k_cell_gemm(const float* __restrict__ xc,
                                                   const float* __restrict__ W,
                                                   unsigned short* __restrict__ h_c) {
    __shared__ float Ws[8 * 64];
    for (int i = threadIdx.x; i < 512; i += 256) Ws[i] = W[i];
    __syncthreads();
    int t = blockIdx.x * 256 + threadIdx.x;       // (cell, j4), 200000*16
    int cell = t >> 4;
    int j = (t & 15) << 2;
    float4 x0 = *(const float4*)(xc + (size_t)cell * 8);
    float4 x1 = *(const float4*)(xc + (size_t)cell * 8 + 4);
    float xk[8] = {x0.x, x0.y, x0.z, x0.w, x1.x, x1.y, x1.z, x1.w};
    float a0 = 0.f, a1 = 0.f, a2 = 0.f, a3 = 0.f;
#pragma unroll
    for (int k = 0; k < 8; ++k) {
        float4 w = *(const float4*)(Ws + k * 64 + j);
        a0 += xk[k] * w.x; a1 += xk[k] * w.y; a2 += xk[k] * w.z; a3 += xk[k] * w.w;
    }
    ushort4 o; o.x = f2bf(a0); o.y = f2bf(a1); o.z = f2bf(a2); o.w = f2bf(a3);
    *(ushort4*)(h_c + ((size_t)cell << 6) + j) = o;
}

// ---------------- scatter: acc[dst] += feat[src] * ea (f32 atomics) ----------------
template <int LOGD>
__global__ __launch_bounds__(256) void k_scatter(const unsigned short* __restrict__ feat,
                                                 const int* __restrict__ src,
                                                 const int* __restrict__ dst,
                                                 const float* __restrict__ ea,
                                                 float* __restrict__ acc, int nE) {
    const int CH = 1 << (LOGD - 2);               // float4 chunks per row
    int t = blockIdx.x * 256 + threadIdx.x;
    if (t >= nE * CH) return;
    int e = t >> (LOGD - 2);
    int c = (t & (CH - 1)) << 2;
    int s = src[e], d = dst[e];
    float w = ea[e];
    ushort4 h = *(const ushort4*)(feat + ((size_t)s << LOGD) + c);
    float* a = acc + ((size_t)d << LOGD) + c;
    atomicAdd(a + 0, w * bf2f(h.x));
    atomicAdd(a + 1, w * bf2f(h.y));
    atomicAdd(a + 2, w * bf2f(h.z));
    atomicAdd(a + 3, w * bf2f(h.w));
}

// ---------------- stage C: h_f = [y_face | x_face] @ W_fp (bf16) ----------------
__global__ __launch_bounds__(256) void k_face_gemm(const float* __restrict__ y_face,
                                                   const float* __restrict__ x_face,
                                                   const float* __restrict__ W_fp,
                                                   unsigned short* __restrict__ h_f) {
    __shared__ float Ws[72 * 128];                // 36.9 KB
    for (int i = threadIdx.x; i < 72 * 128; i += 256) Ws[i] = W_fp[i];
    __syncthreads();
    const int j = (threadIdx.x & 31) << 2;        // 0..124
    const int fsub = threadIdx.x >> 5;            // 0..7
    const int fbase = blockIdx.x * 32 + fsub * 4; // 4 faces per thread
    float acc[4][4] = {};
    for (int k0 = 0; k0 < 64; k0 += 4) {
        float4 rv[4];
#pragma unroll
        for (int r = 0; r < 4; ++r)
            rv[r] = *(const float4*)(y_face + (size_t)(fbase + r) * 64 + k0);
#pragma unroll
        for (int kk = 0; kk < 4; ++kk) {
            float4 w = *(const float4*)(Ws + (k0 + kk) * 128 + j);
#pragma unroll
            for (int r = 0; r < 4; ++r) {
                float rk = ((const float*)&rv[r])[kk];
                acc[r][0] += rk * w.x; acc[r][1] += rk * w.y;
                acc[r][2] += rk * w.z; acc[r][3] += rk * w.w;
            }
        }
    }
    for (int k0 = 0; k0 < 8; k0 += 4) {
        float4 rv[4];
#pragma unroll
        for (int r = 0; r < 4; ++r)
            rv[r] = *(const float4*)(x_face + (size_t)(fbase + r) * 8 + k0);
#pragma unroll
        for (int kk = 0; kk < 4; ++kk) {
            float4 w = *(const float4*)(Ws + (64 + k0 + kk) * 128 + j);
#pragma unroll
            for (int r = 0; r < 4; ++r) {
                float rk = ((const float*)&rv[r])[kk];
                acc[r][0] += rk * w.x; acc[r][1] += rk * w.y;
                acc[r][2] += rk * w.z; acc[r][3] += rk * w.w;
            }
        }
    }
#pragma unroll
    for (int r = 0; r < 4; ++r) {
        ushort4 o; o.x = f2bf(acc[r][0]); o.y = f2bf(acc[r][1]);
        o.z = f2bf(acc[r][2]); o.w = f2bf(acc[r][3]);
        *(ushort4*)(h_f + (size_t)(fbase + r) * 128 + j) = o;
    }
}

// ---------------- stage E: g = y_pt@W_pp (bf16), out = y_pt@W_root + b_pp ----------------
__global__ __launch_bounds__(256) void k_point_gemm(const float* __restrict__ y_pt,
                                                    const float* __restrict__ W_pp,
                                                    const float* __restrict__ W_rt,
                                                    const float* __restrict__ b_pp,
                                                    unsigned short* __restrict__ g,
                                                    float* __restrict__ out) {
    __shared__ float Wa[128 * 64];                // W_pp[:, half]
    __shared__ float Wb[128 * 64];                // W_root[:, half]
    const int jh = blockIdx.y;                    // 0/1
    for (int i = threadIdx.x; i < 128 * 64; i += 256) {
        int k = i >> 6, jj = i & 63;
        Wa[i] = W_pp[k * 128 + jh * 64 + jj];
        Wb[i] = W_rt[k * 128 + jh * 64 + jj];
    }
    __syncthreads();
    const int j = (threadIdx.x & 15) << 2;        // 0..60 (within half)
    const int psub = threadIdx.x >> 4;            // 0..15
    const int pbase = blockIdx.x * 64 + psub * 4; // 4 rows per thread
    float accA[4][4] = {}, accB[4][4] = {};
    for (int k0 = 0; k0 < 128; k0 += 4) {
        float4 rv[4];
#pragma unroll
        for (int r = 0; r < 4; ++r)
            rv[r] = *(const float4*)(y_pt + (size_t)(pbase + r) * 128 + k0);
#pragma unroll
        for (int kk = 0; kk < 4; ++kk) {
            float4 wa = *(const float4*)(Wa + (k0 + kk) * 64 + j);
            float4 wb = *(const float4*)(Wb + (k0 + kk) * 64 + j);
#pragma unroll
            for (int r = 0; r < 4; ++r) {
                float rk = ((const float*)&rv[r])[kk];
                accA[r][0] += rk * wa.x; accA[r][1] += rk * wa.y;
                accA[r][2] += rk * wa.z; accA[r][3] += rk * wa.w;
                accB[r][0] += rk * wb.x; accB[r][1] += rk * wb.y;
                accB[r][2] += rk * wb.z; accB[r][3] += rk * wb.w;
            }
        }
    }
    float4 bp = *(const float4*)(b_pp + jh * 64 + j);
#pragma unroll
    for (int r = 0; r < 4; ++r) {
        ushort4 o; o.x = f2bf(accA[r][0]); o.y = f2bf(accA[r][1]);
        o.z = f2bf(accA[r][2]); o.w = f2bf(accA[r][3]);
        *(ushort4*)(g + (size_t)(pbase + r) * 128 + jh * 64 + j) = o;
        float4 ov; ov.x = accB[r][0] + bp.x; ov.y = accB[r][1] + bp.y;
        ov.z = accB[r][2] + bp.z; ov.w = accB[r][3] + bp.w;
        *(float4*)(out + (size_t)(pbase + r) * 128 + jh * 64 + j) = ov;
    }
}

extern "C" void kernel_launch(void* const* d_in, const int* in_sizes, int n_in,
                              void* d_out, int out_size, void* d_ws, size_t ws_size,
                              hipStream_t stream) {
    const float* x_centers = (const float*)d_in[0];
    const float* x_face    = (const float*)d_in[1];
    const float* W_cf      = (const float*)d_in[2];
    const float* b_cf      = (const float*)d_in[3];
    const float* W_fp      = (const float*)d_in[4];
    const float* b_fp      = (const float*)d_in[5];
    const float* W_pp      = (const float*)d_in[6];
    const float* W_rt      = (const float*)d_in[7];
    const float* b_pp      = (const float*)d_in[8];
    const float* ea_cf     = (const float*)d_in[9];
    const float* ea_fp     = (const float*)d_in[10];
    const float* ea_pp     = (const float*)d_in[11];
    const int* src_cf      = (const int*)d_in[12];
    const int* dst_cf      = (const int*)d_in[13];
    const int* src_fp      = (const int*)d_in[14];
    const int* dst_fp      = (const int*)d_in[15];
    const int* src_pp      = (const int*)d_in[16];
    const int* dst_pp      = (const int*)d_in[17];
    float* out = (float*)d_out;

    char* ws = (char*)d_ws;
    float* y_face        = (float*)(ws + 0);            // 102.4 MB f32 [400k,64]
    float* y_pt          = (float*)(ws + 102400000);    // 102.4 MB f32 [200k,128]
    unsigned short* h_f  = (unsigned short*)(ws + 204800000); // 102.4 MB bf16 [400k,128]
    unsigned short* h_c  = (unsigned short*)(ws + 307200000); //  25.6 MB bf16 [200k,64]
    unsigned short* g    = (unsigned short*)(ws + 0);   // aliases y_face (dead after face gemm)

    // stage A + inits
    k_init_bias<<<25000, 256, 0, stream>>>(y_face, b_cf, 6400000, 15);
    k_init_bias<<<25000, 256, 0, stream>>>(y_pt, b_fp, 6400000, 31);
    k_cell_gemm<<<12500, 256, 0, stream>>>(x_centers, W_cf, h_c);
    // stage B: cells -> faces
    k_scatter<6><<<50000, 256, 0, stream>>>(h_c, src_cf, dst_cf, ea_cf, y_face, E_CF);
    // stage C: face gemm
    k_face_gemm<<<12500, 256, 0, stream>>>(y_face, x_face, W_fp, h_f);
    // stage D: faces -> points
    k_scatter<7><<<100000, 256, 0, stream>>>(h_f, src_fp, dst_fp, ea_fp, y_pt, E_FP);
    // stage E: point gemms (g + root term into out)
    k_point_gemm<<<dim3(3125, 2), 256, 0, stream>>>(y_pt, W_pp, W_rt, b_pp, g, out);
    // stage F: points -> points aggregation
    k_scatter<7><<<150000, 256, 0, stream>>>(g, src_pp, dst_pp, ea_pp, out, E_PP);
}

// Round 4
// 1068.095 us; speedup vs baseline: 4.1538x; 4.1538x over previous
//
#include <hip/hip_runtime.h>
#include <hip/hip_bf16.h>

#define N_CELLS  200000
#define N_FACES  400000
#define N_POINTS 200000
#define E_CF     800000
#define E_FP     800000
#define E_PP     1200000
#define SCAN_TILE 1024

__device__ __forceinline__ float bf2f(unsigned short u) {
    union { unsigned int i; float f; } v; v.i = ((unsigned int)u) << 16; return v.f;
}
__device__ __forceinline__ unsigned short f2bf(float f) {
    __hip_bfloat16 h = __float2bfloat16(f);
    return *reinterpret_cast<unsigned short*>(&h);
}

// ======================= CSR build =======================
__global__ __launch_bounds__(256) void k_zero_i(int* __restrict__ p, int n) {
    int t = blockIdx.x * 256 + threadIdx.x;
    if (t < n) p[t] = 0;
}

__global__ __launch_bounds__(256) void k_hist(const int* __restrict__ dst,
                                              int* __restrict__ cnt, int nE) {
    int t = blockIdx.x * 256 + threadIdx.x;
    if (t < nE) atomicAdd(&cnt[dst[t]], 1);
}

// block b reduces cnt[b*1024 .. b*1024+1023] -> bsum[b]
__global__ __launch_bounds__(256) void k_scan1(const int* __restrict__ cnt, int n,
                                               int* __restrict__ bsum) {
    __shared__ int sh[256];
    int base = blockIdx.x * SCAN_TILE + threadIdx.x * 4;
    int s = 0;
#pragma unroll
    for (int i = 0; i < 4; ++i) { int idx = base + i; if (idx < n) s += cnt[idx]; }
    sh[threadIdx.x] = s;
    __syncthreads();
    for (int off = 128; off > 0; off >>= 1) {
        if (threadIdx.x < off) sh[threadIdx.x] += sh[threadIdx.x + off];
        __syncthreads();
    }
    if (threadIdx.x == 0) bsum[blockIdx.x] = sh[0];
}

// single block: bsum[0..nb) -> exclusive scan (nb <= 512)
__global__ __launch_bounds__(512) void k_scan2(int* __restrict__ bsum, int nb) {
    __shared__ int sh[512];
    int t = threadIdx.x;
    int v = (t < nb) ? bsum[t] : 0;
    sh[t] = v;
    __syncthreads();
    for (int off = 1; off < 512; off <<= 1) {
        int add = (t >= off) ? sh[t - off] : 0;
        __syncthreads();
        sh[t] += add;
        __syncthreads();
    }
    if (t < nb) bsum[t] = sh[t] - v;
}

// write rowptr (exclusive) + cursor copy; cnt and cur may alias
__global__ __launch_bounds__(256) void k_scan3(const int* __restrict__ cnt, int n,
                                               const int* __restrict__ bsum,
                                               int* __restrict__ rowptr,
                                               int* __restrict__ cur) {
    __shared__ int sh[256];
    int base = blockIdx.x * SCAN_TILE + threadIdx.x * 4;
    int c[4]; int s = 0;
#pragma unroll
    for (int i = 0; i < 4; ++i) { int idx = base + i; c[i] = (idx < n) ? cnt[idx] : 0; s += c[i]; }
    sh[threadIdx.x] = s;
    __syncthreads();
    int v = s;
    for (int off = 1; off < 256; off <<= 1) {
        int add = (threadIdx.x >= off) ? sh[threadIdx.x - off] : 0;
        __syncthreads();
        sh[threadIdx.x] += add;
        __syncthreads();
    }
    int excl = sh[threadIdx.x] - v + bsum[blockIdx.x];
#pragma unroll
    for (int i = 0; i < 4; ++i) {
        int idx = base + i;
        if (idx < n) {
            rowptr[idx] = excl; cur[idx] = excl; excl += c[i];
            if (idx == n - 1) rowptr[n] = excl;
        }
    }
}

__global__ __launch_bounds__(256) void k_fill(const int* __restrict__ src,
                                              const int* __restrict__ dst,
                                              const float* __restrict__ ea,
                                              int* __restrict__ cur,
                                              int* __restrict__ psrc,
                                              float* __restrict__ pea, int nE) {
    int t = blockIdx.x * 256 + threadIdx.x;
    if (t >= nE) return;
    int d = dst[t];
    int slot = atomicAdd(&cur[d], 1);
    psrc[slot] = src[t];
    pea[slot] = ea[t];
}

// ======================= gather-reduce =======================
// one wave per dst row, D=64: lane = column
__global__ __launch_bounds__(256) void k_gather64(const unsigned short* __restrict__ feat,
                                                  const int* __restrict__ ptr,
                                                  const int* __restrict__ psrc,
                                                  const float* __restrict__ pea,
                                                  const float* __restrict__ bias,
                                                  float* __restrict__ outp, int nRows) {
    int w = (blockIdx.x * 256 + threadIdx.x) >> 6;
    int lane = threadIdx.x & 63;
    if (w >= nRows) return;
    int beg = ptr[w], end = ptr[w + 1];
    float acc = bias[lane];
    for (int e = beg; e < end; ++e) {
        int s = psrc[e]; float wt = pea[e];
        acc += wt * bf2f(feat[((size_t)s << 6) + lane]);
    }
    outp[((size_t)w << 6) + lane] = acc;
}

// one wave per dst row, D=128: lane handles 2 columns
template <bool ADD>
__global__ __launch_bounds__(256) void k_gather128(const unsigned short* __restrict__ feat,
                                                   const int* __restrict__ ptr,
                                                   const int* __restrict__ psrc,
                                                   const float* __restrict__ pea,
                                                   const float* __restrict__ bias,
                                                   float* __restrict__ io, int nRows) {
    int w = (blockIdx.x * 256 + threadIdx.x) >> 6;
    int lane = threadIdx.x & 63;
    if (w >= nRows) return;
    int beg = ptr[w], end = ptr[w + 1];
    size_t off = ((size_t)w << 7) + lane * 2;
    float a0, a1;
    if (ADD) { float2 v = *(const float2*)(io + off); a0 = v.x; a1 = v.y; }
    else     { a0 = bias[lane * 2]; a1 = bias[lane * 2 + 1]; }
    for (int e = beg; e < end; ++e) {
        int s = psrc[e]; float wt = pea[e];
        ushort2 h = *(const ushort2*)(feat + ((size_t)s << 7) + lane * 2);
        a0 += wt * bf2f(h.x); a1 += wt * bf2f(h.y);
    }
    *(float2*)(io + off) = make_float2(a0, a1);
}

// ======================= dense stages =======================
__global__ __launch_bounds__(256) void k_cell_gemm(const float* __restrict__ xc,
                                                   const float* __restrict__ W,
                                                   unsigned short* __restrict__ h_c) {
    __shared__ float Ws[8 * 64];
    for (int i = threadIdx.x; i < 512; i += 256) Ws[i] = W[i];
    __syncthreads();
    int t = blockIdx.x * 256 + threadIdx.x;
    int cell = t >> 4;
    int j = (t & 15) << 2;
    float4 x0 = *(const float4*)(xc + (size_t)cell * 8);
    float4 x1 = *(const float4*)(xc + (size_t)cell * 8 + 4);
    float xk[8] = {x0.x, x0.y, x0.z, x0.w, x1.x, x1.y, x1.z, x1.w};
    float a0 = 0.f, a1 = 0.f, a2 = 0.f, a3 = 0.f;
#pragma unroll
    for (int k = 0; k < 8; ++k) {
        float4 w = *(const float4*)(Ws + k * 64 + j);
        a0 += xk[k] * w.x; a1 += xk[k] * w.y; a2 += xk[k] * w.z; a3 += xk[k] * w.w;
    }
    ushort4 o; o.x = f2bf(a0); o.y = f2bf(a1); o.z = f2bf(a2); o.w = f2bf(a3);
    *(ushort4*)(h_c + ((size_t)cell << 6) + j) = o;
}

__global__ __launch_bounds__(256) void k_face_gemm(const float* __restrict__ y_face,
                                                   const float* __restrict__ x_face,
                                                   const float* __restrict__ W_fp,
                                                   unsigned short* __restrict__ h_f) {
    __shared__ float Ws[72 * 128];
    for (int i = threadIdx.x; i < 72 * 128; i += 256) Ws[i] = W_fp[i];
    __syncthreads();
    const int j = (threadIdx.x & 31) << 2;
    const int fsub = threadIdx.x >> 5;
    const int fbase = blockIdx.x * 32 + fsub * 4;
    float acc[4][4] = {};
    for (int k0 = 0; k0 < 64; k0 += 4) {
        float4 rv[4];
#pragma unroll
        for (int r = 0; r < 4; ++r)
            rv[r] = *(const float4*)(y_face + (size_t)(fbase + r) * 64 + k0);
#pragma unroll
        for (int kk = 0; kk < 4; ++kk) {
            float4 w = *(const float4*)(Ws + (k0 + kk) * 128 + j);
#pragma unroll
            for (int r = 0; r < 4; ++r) {
                float rk = ((const float*)&rv[r])[kk];
                acc[r][0] += rk * w.x; acc[r][1] += rk * w.y;
                acc[r][2] += rk * w.z; acc[r][3] += rk * w.w;
            }
        }
    }
    for (int k0 = 0; k0 < 8; k0 += 4) {
        float4 rv[4];
#pragma unroll
        for (int r = 0; r < 4; ++r)
            rv[r] = *(const float4*)(x_face + (size_t)(fbase + r) * 8 + k0);
#pragma unroll
        for (int kk = 0; kk < 4; ++kk) {
            float4 w = *(const float4*)(Ws + (64 + k0 + kk) * 128 + j);
#pragma unroll
            for (int r = 0; r < 4; ++r) {
                float rk = ((const float*)&rv[r])[kk];
                acc[r][0] += rk * w.x; acc[r][1] += rk * w.y;
                acc[r][2] += rk * w.z; acc[r][3] += rk * w.w;
            }
        }
    }
#pragma unroll
    for (int r = 0; r < 4; ++r) {
        ushort4 o; o.x = f2bf(acc[r][0]); o.y = f2bf(acc[r][1]);
        o.z = f2bf(acc[r][2]); o.w = f2bf(acc[r][3]);
        *(ushort4*)(h_f + (size_t)(fbase + r) * 128 + j) = o;
    }
}

__global__ __launch_bounds__(256) void k_point_gemm(const float* __restrict__ y_pt,
                                                    const float* __restrict__ W_pp,
                                                    const float* __restrict__ W_rt,
                                                    const float* __restrict__ b_pp,
                                                    unsigned short* __restrict__ g,
                                                    float* __restrict__ out) {
    __shared__ float Wa[128 * 64];
    __shared__ float Wb[128 * 64];
    const int jh = blockIdx.y;
    for (int i = threadIdx.x; i < 128 * 64; i += 256) {
        int k = i >> 6, jj = i & 63;
        Wa[i] = W_pp[k * 128 + jh * 64 + jj];
        Wb[i] = W_rt[k * 128 + jh * 64 + jj];
    }
    __syncthreads();
    const int j = (threadIdx.x & 15) << 2;
    const int psub = threadIdx.x >> 4;
    const int pbase = blockIdx.x * 64 + psub * 4;
    float accA[4][4] = {}, accB[4][4] = {};
    for (int k0 = 0; k0 < 128; k0 += 4) {
        float4 rv[4];
#pragma unroll
        for (int r = 0; r < 4; ++r)
            rv[r] = *(const float4*)(y_pt + (size_t)(pbase + r) * 128 + k0);
#pragma unroll
        for (int kk = 0; kk < 4; ++kk) {
            float4 wa = *(const float4*)(Wa + (k0 + kk) * 64 + j);
            float4 wb = *(const float4*)(Wb + (k0 + kk) * 64 + j);
#pragma unroll
            for (int r = 0; r < 4; ++r) {
                float rk = ((const float*)&rv[r])[kk];
                accA[r][0] += rk * wa.x; accA[r][1] += rk * wa.y;
                accA[r][2] += rk * wa.z; accA[r][3] += rk * wa.w;
                accB[r][0] += rk * wb.x; accB[r][1] += rk * wb.y;
                accB[r][2] += rk * wb.z; accB[r][3] += rk * wb.w;
            }
        }
    }
    float4 bp = *(const float4*)(b_pp + jh * 64 + j);
#pragma unroll
    for (int r = 0; r < 4; ++r) {
        ushort4 o; o.x = f2bf(accA[r][0]); o.y = f2bf(accA[r][1]);
        o.z = f2bf(accA[r][2]); o.w = f2bf(accA[r][3]);
        *(ushort4*)(g + (size_t)(pbase + r) * 128 + jh * 64 + j) = o;
        float4 ov; ov.x = accB[r][0] + bp.x; ov.y = accB[r][1] + bp.y;
        ov.z = accB[r][2] + bp.z; ov.w = accB[r][3] + bp.w;
        *(float4*)(out + (size_t)(pbase + r) * 128 + jh * 64 + j) = ov;
    }
}

extern "C" void kernel_launch(void* const* d_in, const int* in_sizes, int n_in,
                              void* d_out, int out_size, void* d_ws, size_t ws_size,
                              hipStream_t stream) {
    const float* x_centers = (const float*)d_in[0];
    const float* x_face    = (const float*)d_in[1];
    const float* W_cf      = (const float*)d_in[2];
    const float* b_cf      = (const float*)d_in[3];
    const float* W_fp      = (const float*)d_in[4];
    const float* b_fp      = (const float*)d_in[5];
    const float* W_pp      = (const float*)d_in[6];
    const float* W_rt      = (const float*)d_in[7];
    const float* b_pp      = (const float*)d_in[8];
    const float* ea_cf     = (const float*)d_in[9];
    const float* ea_fp     = (const float*)d_in[10];
    const float* ea_pp     = (const float*)d_in[11];
    const int* src_cf      = (const int*)d_in[12];
    const int* dst_cf      = (const int*)d_in[13];
    const int* src_fp      = (const int*)d_in[14];
    const int* dst_fp      = (const int*)d_in[15];
    const int* src_pp      = (const int*)d_in[16];
    const int* dst_pp      = (const int*)d_in[17];
    float* out = (float*)d_out;

    char* ws = (char*)d_ws;
    // persistent buffers (total 332.8 MB, same footprint round 3 proved OK)
    float* y_face       = (float*)(ws + 0);              // f32 [400k,64]  dead after face_gemm
    float* y_pt         = (float*)(ws + 102400000);      // f32 [200k,128]
    unsigned short* h_f = (unsigned short*)(ws + 204800000); // bf16 [400k,128] written step5
    unsigned short* h_c = (unsigned short*)(ws + 307200000); // bf16 [200k,64] dead after gatherB
    unsigned short* g   = (unsigned short*)(ws + 0);     // bf16 [200k,128] aliases y_face

    // CSR_cf aliases h_f region (dead before face_gemm writes h_f)
    int*   cf_ptr = (int*)(ws + 204800000);              // 400001
    int*   cf_cur = (int*)(ws + 206400004);              // 400000 (counts/cursor)
    int*   cf_src = (int*)(ws + 208000004);              // 800000
    float* cf_ea  = (float*)(ws + 211200004);            // 800000
    int*   bsum1  = (int*)(ws + 214400004);              // 512
    // CSR_fp + CSR_pp alias h_c region (built after gatherB)
    int*   fp_ptr = (int*)(ws + 307200000);              // 200001
    int*   fp_cur = (int*)(ws + 308000004);              // 200000
    int*   fp_src = (int*)(ws + 308800004);              // 800000
    float* fp_ea  = (float*)(ws + 312000004);            // 800000
    int*   pp_ptr = (int*)(ws + 315200004);              // 200001
    int*   pp_cur = (int*)(ws + 316000008);              // 200000
    int*   pp_src = (int*)(ws + 316800008);              // 1200000
    float* pp_ea  = (float*)(ws + 321600008);            // 1200000
    int*   bsum2  = (int*)(ws + 326400008);              // 512

    // ---- build CSR_cf ----
    k_zero_i<<<1563, 256, 0, stream>>>(cf_cur, N_FACES);
    k_hist<<<3125, 256, 0, stream>>>(dst_cf, cf_cur, E_CF);
    k_scan1<<<391, 256, 0, stream>>>(cf_cur, N_FACES, bsum1);
    k_scan2<<<1, 512, 0, stream>>>(bsum1, 391);
    k_scan3<<<391, 256, 0, stream>>>(cf_cur, N_FACES, bsum1, cf_ptr, cf_cur);
    k_fill<<<3125, 256, 0, stream>>>(src_cf, dst_cf, ea_cf, cf_cur, cf_src, cf_ea, E_CF);
    // ---- stage A: cell gemm ----
    k_cell_gemm<<<12500, 256, 0, stream>>>(x_centers, W_cf, h_c);
    // ---- gather B: cells -> faces ----
    k_gather64<<<100000, 256, 0, stream>>>(h_c, cf_ptr, cf_src, cf_ea, b_cf, y_face, N_FACES);
    // ---- build CSR_fp (h_c now dead) ----
    k_zero_i<<<782, 256, 0, stream>>>(fp_cur, N_POINTS);
    k_hist<<<3125, 256, 0, stream>>>(dst_fp, fp_cur, E_FP);
    k_scan1<<<196, 256, 0, stream>>>(fp_cur, N_POINTS, bsum2);
    k_scan2<<<1, 512, 0, stream>>>(bsum2, 196);
    k_scan3<<<196, 256, 0, stream>>>(fp_cur, N_POINTS, bsum2, fp_ptr, fp_cur);
    k_fill<<<3125, 256, 0, stream>>>(src_fp, dst_fp, ea_fp, fp_cur, fp_src, fp_ea, E_FP);
    // ---- build CSR_pp ----
    k_zero_i<<<782, 256, 0, stream>>>(pp_cur, N_POINTS);
    k_hist<<<4688, 256, 0, stream>>>(dst_pp, pp_cur, E_PP);
    k_scan1<<<196, 256, 0, stream>>>(pp_cur, N_POINTS, bsum2);
    k_scan2<<<1, 512, 0, stream>>>(bsum2, 196);
    k_scan3<<<196, 256, 0, stream>>>(pp_cur, N_POINTS, bsum2, pp_ptr, pp_cur);
    k_fill<<<4688, 256, 0, stream>>>(src_pp, dst_pp, ea_pp, pp_cur, pp_src, pp_ea, E_PP);
    // ---- stage C: face gemm ----
    k_face_gemm<<<12500, 256, 0, stream>>>(y_face, x_face, W_fp, h_f);
    // ---- gather D: faces -> points ----
    k_gather128<false><<<50000, 256, 0, stream>>>(h_f, fp_ptr, fp_src, fp_ea, b_fp, y_pt, N_POINTS);
    // ---- stage E: point gemms (g + root term into out) ----
    k_point_gemm<<<dim3(3125, 2), 256, 0, stream>>>(y_pt, W_pp, W_rt, b_pp, g, out);
    // ---- gather F: points -> points, add in place ----
    k_gather128<true><<<50000, 256, 0, stream>>>(g, pp_ptr, pp_src, pp_ea, nullptr, out, N_POINTS);
}

// Round 5
// 873.615 us; speedup vs baseline: 5.0785x; 1.2226x over previous
//
#include <hip/hip_runtime.h>
#include <hip/hip_bf16.h>

#define N_CELLS  200000
#define N_FACES  400000
#define N_POINTS 200000
#define E_CF     800000
#define E_FP     800000
#define E_PP     1200000
#define SCAN_TILE 1024

typedef __attribute__((ext_vector_type(8))) short bf16x8;
typedef __attribute__((ext_vector_type(4))) float f32x4;

__device__ __forceinline__ float bf2f(unsigned short u) {
    union { unsigned int i; float f; } v; v.i = ((unsigned int)u) << 16; return v.f;
}
__device__ __forceinline__ unsigned short f2bf(float f) {
    __hip_bfloat16 h = __float2bfloat16(f);
    return *reinterpret_cast<unsigned short*>(&h);
}

// ======================= CSR build =======================
__global__ __launch_bounds__(256) void k_zero_i(int* __restrict__ p, int n) {
    int t = blockIdx.x * 256 + threadIdx.x;
    if (t < n) p[t] = 0;
}

__global__ __launch_bounds__(256) void k_hist(const int* __restrict__ dst,
                                              int* __restrict__ cnt, int nE) {
    int t = blockIdx.x * 256 + threadIdx.x;
    if (t < nE) atomicAdd(&cnt[dst[t]], 1);
}

__global__ __launch_bounds__(256) void k_scan1(const int* __restrict__ cnt, int n,
                                               int* __restrict__ bsum) {
    __shared__ int sh[256];
    int base = blockIdx.x * SCAN_TILE + threadIdx.x * 4;
    int s = 0;
#pragma unroll
    for (int i = 0; i < 4; ++i) { int idx = base + i; if (idx < n) s += cnt[idx]; }
    sh[threadIdx.x] = s;
    __syncthreads();
    for (int off = 128; off > 0; off >>= 1) {
        if (threadIdx.x < off) sh[threadIdx.x] += sh[threadIdx.x + off];
        __syncthreads();
    }
    if (threadIdx.x == 0) bsum[blockIdx.x] = sh[0];
}

__global__ __launch_bounds__(512) void k_scan2(int* __restrict__ bsum, int nb) {
    __shared__ int sh[512];
    int t = threadIdx.x;
    int v = (t < nb) ? bsum[t] : 0;
    sh[t] = v;
    __syncthreads();
    for (int off = 1; off < 512; off <<= 1) {
        int add = (t >= off) ? sh[t - off] : 0;
        __syncthreads();
        sh[t] += add;
        __syncthreads();
    }
    if (t < nb) bsum[t] = sh[t] - v;
}

__global__ __launch_bounds__(256) void k_scan3(const int* __restrict__ cnt, int n,
                                               const int* __restrict__ bsum,
                                               int* __restrict__ rowptr,
                                               int* __restrict__ cur) {
    __shared__ int sh[256];
    int base = blockIdx.x * SCAN_TILE + threadIdx.x * 4;
    int c[4]; int s = 0;
#pragma unroll
    for (int i = 0; i < 4; ++i) { int idx = base + i; c[i] = (idx < n) ? cnt[idx] : 0; s += c[i]; }
    sh[threadIdx.x] = s;
    __syncthreads();
    int v = s;
    for (int off = 1; off < 256; off <<= 1) {
        int add = (threadIdx.x >= off) ? sh[threadIdx.x - off] : 0;
        __syncthreads();
        sh[threadIdx.x] += add;
        __syncthreads();
    }
    int excl = sh[threadIdx.x] - v + bsum[blockIdx.x];
#pragma unroll
    for (int i = 0; i < 4; ++i) {
        int idx = base + i;
        if (idx < n) {
            rowptr[idx] = excl; cur[idx] = excl; excl += c[i];
            if (idx == n - 1) rowptr[n] = excl;
        }
    }
}

__global__ __launch_bounds__(256) void k_fill(const int* __restrict__ src,
                                              const int* __restrict__ dst,
                                              const float* __restrict__ ea,
                                              int* __restrict__ cur,
                                              int* __restrict__ psrc,
                                              float* __restrict__ pea, int nE) {
    int t = blockIdx.x * 256 + threadIdx.x;
    if (t >= nE) return;
    int d = dst[t];
    int slot = atomicAdd(&cur[d], 1);
    psrc[slot] = src[t];
    pea[slot] = ea[t];
}

// ======================= weight packing (fragment order) =======================
// Bp[((ks*NCT+ct)*64+lane)*8+j] = W[k = ks*32+(lane>>4)*8+j][col = ct*16+(lane&15)]
__global__ __launch_bounds__(256) void k_pack_pt(const float* __restrict__ W_rt,
                                                 const float* __restrict__ W_pp,
                                                 unsigned short* __restrict__ Bp) {
    int t = blockIdx.x * 256 + threadIdx.x;       // 4*16*64*8 = 32768
    int j = t & 7, lane = (t >> 3) & 63, ct = (t >> 9) & 15, ks = t >> 13;
    int k = ks * 32 + (lane >> 4) * 8 + j;
    int col = ct * 16 + (lane & 15);
    float v = (col < 128) ? W_rt[k * 128 + col] : W_pp[k * 128 + (col - 128)];
    Bp[t] = f2bf(v);
}

__global__ __launch_bounds__(256) void k_pack_face(const float* __restrict__ W_fp,
                                                   unsigned short* __restrict__ Bp) {
    int t = blockIdx.x * 256 + threadIdx.x;       // 3*8*64*8 = 12288
    int j = t & 7, lane = (t >> 3) & 63, ct = (t >> 9) & 7, ks = t >> 12;
    int k = ks * 32 + (lane >> 4) * 8 + j;
    int col = ct * 16 + (lane & 15);
    float v = (k < 72) ? W_fp[k * 128 + col] : 0.f; // zero rows mask the A pad cols
    Bp[t] = f2bf(v);
}

// ======================= gather-reduce =======================
// cells->faces: one wave per face row; writes bf16 padded row [96] and x_face cols
__global__ __launch_bounds__(256) void k_gather64(const unsigned short* __restrict__ feat,
                                                  const int* __restrict__ ptr,
                                                  const int* __restrict__ psrc,
                                                  const float* __restrict__ pea,
                                                  const float* __restrict__ bias,
                                                  const float* __restrict__ x_face,
                                                  unsigned short* __restrict__ yfp,
                                                  int nRows) {
    int w = (blockIdx.x * 256 + threadIdx.x) >> 6;
    int lane = threadIdx.x & 63;
    if (w >= nRows) return;
    int beg = ptr[w], end = ptr[w + 1];
    float acc = bias[lane];
    for (int e = beg; e < end; ++e)
        acc += pea[e] * bf2f(feat[((size_t)psrc[e] << 6) + lane]);
    yfp[(size_t)w * 96 + lane] = f2bf(acc);
    if (lane < 8) yfp[(size_t)w * 96 + 64 + lane] = f2bf(x_face[w * 8 + lane]);
}

// faces->points: one wave per point row, D=128, writes bf16
__global__ __launch_bounds__(256) void k_gather128_bf(const unsigned short* __restrict__ feat,
                                                      const int* __restrict__ ptr,
                                                      const int* __restrict__ psrc,
                                                      const float* __restrict__ pea,
                                                      const float* __restrict__ bias,
                                                      unsigned short* __restrict__ o,
                                                      int nRows) {
    int w = (blockIdx.x * 256 + threadIdx.x) >> 6;
    int lane = threadIdx.x & 63;
    if (w >= nRows) return;
    int beg = ptr[w], end = ptr[w + 1];
    float a0 = bias[lane * 2], a1 = bias[lane * 2 + 1];
    for (int e = beg; e < end; ++e) {
        int s = psrc[e]; float wt = pea[e];
        ushort2 h = *(const ushort2*)(feat + ((size_t)s << 7) + lane * 2);
        a0 += wt * bf2f(h.x); a1 += wt * bf2f(h.y);
    }
    ushort2 o2; o2.x = f2bf(a0); o2.y = f2bf(a1);
    *(ushort2*)(o + ((size_t)w << 7) + lane * 2) = o2;
}

// points->points: one wave per point row, adds into f32 out
__global__ __launch_bounds__(256) void k_gather128_add(const unsigned short* __restrict__ feat,
                                                       const int* __restrict__ ptr,
                                                       const int* __restrict__ psrc,
                                                       const float* __restrict__ pea,
                                                       float* __restrict__ io, int nRows) {
    int w = (blockIdx.x * 256 + threadIdx.x) >> 6;
    int lane = threadIdx.x & 63;
    if (w >= nRows) return;
    int beg = ptr[w], end = ptr[w + 1];
    size_t off = ((size_t)w << 7) + lane * 2;
    float2 v = *(const float2*)(io + off);
    float a0 = v.x, a1 = v.y;
    for (int e = beg; e < end; ++e) {
        int s = psrc[e]; float wt = pea[e];
        ushort2 h = *(const ushort2*)(feat + ((size_t)s << 7) + lane * 2);
        a0 += wt * bf2f(h.x); a1 += wt * bf2f(h.y);
    }
    *(float2*)(io + off) = make_float2(a0, a1);
}

// ======================= dense stages =======================
__global__ __launch_bounds__(256) void k_cell_gemm(const float* __restrict__ xc,
                                                   const float* __restrict__ W,
                                                   unsigned short* __restrict__ h_c) {
    __shared__ float Ws[8 * 64];
    for (int i = threadIdx.x; i < 512; i += 256) Ws[i] = W[i];
    __syncthreads();
    int t = blockIdx.x * 256 + threadIdx.x;
    int cell = t >> 4;
    int j = (t & 15) << 2;
    float4 x0 = *(const float4*)(xc + (size_t)cell * 8);
    float4 x1 = *(const float4*)(xc + (size_t)cell * 8 + 4);
    float xk[8] = {x0.x, x0.y, x0.z, x0.w, x1.x, x1.y, x1.z, x1.w};
    float a0 = 0.f, a1 = 0.f, a2 = 0.f, a3 = 0.f;
#pragma unroll
    for (int k = 0; k < 8; ++k) {
        float4 w = *(const float4*)(Ws + k * 64 + j);
        a0 += xk[k] * w.x; a1 += xk[k] * w.y; a2 += xk[k] * w.z; a3 += xk[k] * w.w;
    }
    ushort4 o; o.x = f2bf(a0); o.y = f2bf(a1); o.z = f2bf(a2); o.w = f2bf(a3);
    *(ushort4*)(h_c + ((size_t)cell << 6) + j) = o;
}

// face MFMA: [400k,96(bf16)] @ [96,128] -> h_f bf16. block=4 waves (2 row-grp x 2 col-grp)
__global__ __launch_bounds__(256) void k_face_mfma(const unsigned short* __restrict__ A,
                                                   const unsigned short* __restrict__ Bp,
                                                   unsigned short* __restrict__ h_f) {
    const int w = threadIdx.x >> 6;
    const int lane = threadIdx.x & 63;
    const int rg = w >> 1, cg = w & 1;
    const int row0 = blockIdx.x * 32 + rg * 16;
    bf16x8 bfr[3][4];
#pragma unroll
    for (int ks = 0; ks < 3; ++ks)
#pragma unroll
        for (int c = 0; c < 4; ++c) {
            int ct = cg * 4 + c;
            bfr[ks][c] = *(const bf16x8*)(Bp + ((size_t)(ks * 8 + ct) * 64 + lane) * 8);
        }
    f32x4 acc[4] = {};
    const unsigned short* arow = A + (size_t)(row0 + (lane & 15)) * 96 + ((lane >> 4) * 8);
#pragma unroll
    for (int ks = 0; ks < 3; ++ks) {
        bf16x8 af = *(const bf16x8*)(arow + ks * 32);
#pragma unroll
        for (int c = 0; c < 4; ++c)
            acc[c] = __builtin_amdgcn_mfma_f32_16x16x32_bf16(af, bfr[ks][c], acc[c], 0, 0, 0);
    }
    const int rbase = row0 + (lane >> 4) * 4;
#pragma unroll
    for (int c = 0; c < 4; ++c) {
        int gcol = cg * 64 + c * 16 + (lane & 15);
#pragma unroll
        for (int r = 0; r < 4; ++r)
            h_f[(size_t)(rbase + r) * 128 + gcol] = f2bf(acc[c][r]);
    }
}

// point MFMA: [200k,128(bf16)] @ [128,256] ; cols 0-127 -> out(f32)+bias, 128-255 -> g(bf16)
__global__ __launch_bounds__(256) void k_point_mfma(const unsigned short* __restrict__ A,
                                                    const unsigned short* __restrict__ Bp,
                                                    const float* __restrict__ b_pp,
                                                    unsigned short* __restrict__ g,
                                                    float* __restrict__ out) {
    const int w = threadIdx.x >> 6;
    const int lane = threadIdx.x & 63;
    const int row0 = blockIdx.x * 16;
    bf16x8 bfr[4][4];
#pragma unroll
    for (int ks = 0; ks < 4; ++ks)
#pragma unroll
        for (int c = 0; c < 4; ++c) {
            int ct = w * 4 + c;
            bfr[ks][c] = *(const bf16x8*)(Bp + ((size_t)(ks * 16 + ct) * 64 + lane) * 8);
        }
    f32x4 acc[4] = {};
    const unsigned short* arow = A + (size_t)(row0 + (lane & 15)) * 128 + ((lane >> 4) * 8);
#pragma unroll
    for (int ks = 0; ks < 4; ++ks) {
        bf16x8 af = *(const bf16x8*)(arow + ks * 32);
#pragma unroll
        for (int c = 0; c < 4; ++c)
            acc[c] = __builtin_amdgcn_mfma_f32_16x16x32_bf16(af, bfr[ks][c], acc[c], 0, 0, 0);
    }
    const int rbase = row0 + (lane >> 4) * 4;
    if (w < 2) {
#pragma unroll
        for (int c = 0; c < 4; ++c) {
            int gcol = w * 64 + c * 16 + (lane & 15);
            float bias = b_pp[gcol];
#pragma unroll
            for (int r = 0; r < 4; ++r)
                out[(size_t)(rbase + r) * 128 + gcol] = acc[c][r] + bias;
        }
    } else {
#pragma unroll
        for (int c = 0; c < 4; ++c) {
            int gcol = (w - 2) * 64 + c * 16 + (lane & 15);
#pragma unroll
            for (int r = 0; r < 4; ++r)
                g[(size_t)(rbase + r) * 128 + gcol] = f2bf(acc[c][r]);
        }
    }
}

extern "C" void kernel_launch(void* const* d_in, const int* in_sizes, int n_in,
                              void* d_out, int out_size, void* d_ws, size_t ws_size,
                              hipStream_t stream) {
    const float* x_centers = (const float*)d_in[0];
    const float* x_face    = (const float*)d_in[1];
    const float* W_cf      = (const float*)d_in[2];
    const float* b_cf      = (const float*)d_in[3];
    const float* W_fp      = (const float*)d_in[4];
    const float* b_fp      = (const float*)d_in[5];
    const float* W_pp      = (const float*)d_in[6];
    const float* W_rt      = (const float*)d_in[7];
    const float* b_pp      = (const float*)d_in[8];
    const float* ea_cf     = (const float*)d_in[9];
    const float* ea_fp     = (const float*)d_in[10];
    const float* ea_pp     = (const float*)d_in[11];
    const int* src_cf      = (const int*)d_in[12];
    const int* dst_cf      = (const int*)d_in[13];
    const int* src_fp      = (const int*)d_in[14];
    const int* dst_fp      = (const int*)d_in[15];
    const int* src_pp      = (const int*)d_in[16];
    const int* dst_pp      = (const int*)d_in[17];
    float* out = (float*)d_out;

    char* ws = (char*)d_ws;
    unsigned short* yfp   = (unsigned short*)(ws + 0);          // bf16 [400k][96] 76.8MB
    unsigned short* g     = (unsigned short*)(ws + 0);          // bf16 [200k][128] aliases yfp (dead)
    unsigned short* h_f   = (unsigned short*)(ws + 76800000);   // bf16 [400k][128] 102.4MB
    unsigned short* y_ptb = (unsigned short*)(ws + 179200000);  // bf16 [200k][128] 51.2MB
    unsigned short* h_c   = (unsigned short*)(ws + 230400000);  // bf16 [200k][64] 25.6MB
    unsigned short* Bp_pt = (unsigned short*)(ws + 256000000);  // 64KB
    unsigned short* Bp_fc = (unsigned short*)(ws + 256065536);  // 24KB
    int*   bsum1  = (int*)(ws + 256090112);
    int*   bsum2  = (int*)(ws + 256092160);
    int*   cf_ptr = (int*)(ws + 256094208);
    int*   cf_cur = (int*)(ws + 257694212);
    int*   cf_src = (int*)(ws + 259294212);
    float* cf_ea  = (float*)(ws + 262494212);
    int*   fp_ptr = (int*)(ws + 265694212);
    int*   fp_cur = (int*)(ws + 266494216);
    int*   fp_src = (int*)(ws + 267294216);
    float* fp_ea  = (float*)(ws + 270494216);
    int*   pp_ptr = (int*)(ws + 273694216);
    int*   pp_cur = (int*)(ws + 274494220);
    int*   pp_src = (int*)(ws + 275294220);
    float* pp_ea  = (float*)(ws + 280094220);                   // ends ~284.9MB

    // ---- weight packing ----
    k_pack_pt<<<128, 256, 0, stream>>>(W_rt, W_pp, Bp_pt);
    k_pack_face<<<48, 256, 0, stream>>>(W_fp, Bp_fc);
    // ---- build CSR_cf ----
    k_zero_i<<<1563, 256, 0, stream>>>(cf_cur, N_FACES);
    k_hist<<<3125, 256, 0, stream>>>(dst_cf, cf_cur, E_CF);
    k_scan1<<<391, 256, 0, stream>>>(cf_cur, N_FACES, bsum1);
    k_scan2<<<1, 512, 0, stream>>>(bsum1, 391);
    k_scan3<<<391, 256, 0, stream>>>(cf_cur, N_FACES, bsum1, cf_ptr, cf_cur);
    k_fill<<<3125, 256, 0, stream>>>(src_cf, dst_cf, ea_cf, cf_cur, cf_src, cf_ea, E_CF);
    // ---- build CSR_fp ----
    k_zero_i<<<782, 256, 0, stream>>>(fp_cur, N_POINTS);
    k_hist<<<3125, 256, 0, stream>>>(dst_fp, fp_cur, E_FP);
    k_scan1<<<196, 256, 0, stream>>>(fp_cur, N_POINTS, bsum2);
    k_scan2<<<1, 512, 0, stream>>>(bsum2, 196);
    k_scan3<<<196, 256, 0, stream>>>(fp_cur, N_POINTS, bsum2, fp_ptr, fp_cur);
    k_fill<<<3125, 256, 0, stream>>>(src_fp, dst_fp, ea_fp, fp_cur, fp_src, fp_ea, E_FP);
    // ---- build CSR_pp ----
    k_zero_i<<<782, 256, 0, stream>>>(pp_cur, N_POINTS);
    k_hist<<<4688, 256, 0, stream>>>(dst_pp, pp_cur, E_PP);
    k_scan1<<<196, 256, 0, stream>>>(pp_cur, N_POINTS, bsum2);
    k_scan2<<<1, 512, 0, stream>>>(bsum2, 196);
    k_scan3<<<196, 256, 0, stream>>>(pp_cur, N_POINTS, bsum2, pp_ptr, pp_cur);
    k_fill<<<4688, 256, 0, stream>>>(src_pp, dst_pp, ea_pp, pp_cur, pp_src, pp_ea, E_PP);
    // ---- stage A: cell gemm ----
    k_cell_gemm<<<12500, 256, 0, stream>>>(x_centers, W_cf, h_c);
    // ---- gather B: cells -> faces (bf16 padded rows + x_face merge) ----
    k_gather64<<<100000, 256, 0, stream>>>(h_c, cf_ptr, cf_src, cf_ea, b_cf, x_face, yfp, N_FACES);
    // ---- stage C: face MFMA ----
    k_face_mfma<<<12500, 256, 0, stream>>>(yfp, Bp_fc, h_f);
    // ---- gather D: faces -> points (bf16 out) ----
    k_gather128_bf<<<50000, 256, 0, stream>>>(h_f, fp_ptr, fp_src, fp_ea, b_fp, y_ptb, N_POINTS);
    // ---- stage E: point MFMA (g bf16 + root/bias f32 into out) ----
    k_point_mfma<<<12500, 256, 0, stream>>>(y_ptb, Bp_pt, b_pp, g, out);
    // ---- gather F: points -> points, add in place ----
    k_gather128_add<<<50000, 256, 0, stream>>>(g, pp_ptr, pp_src, pp_ea, out, N_POINTS);
}

// Round 6
// 588.254 us; speedup vs baseline: 7.5421x; 1.4851x over previous
//
#include <hip/hip_runtime.h>
#include <hip/hip_bf16.h>

#define N_CELLS  200000
#define N_FACES  400000
#define N_POINTS 200000
#define E_CF     800000
#define E_FP     800000
#define E_PP     1200000
#define SCAN_TILE 1024

typedef __attribute__((ext_vector_type(8))) short bf16x8;
typedef __attribute__((ext_vector_type(4))) float f32x4;

__device__ __forceinline__ float bf2f(unsigned short u) {
    union { unsigned int i; float f; } v; v.i = ((unsigned int)u) << 16; return v.f;
}
__device__ __forceinline__ unsigned short f2bf(float f) {
    __hip_bfloat16 h = __float2bfloat16(f);
    return *reinterpret_cast<unsigned short*>(&h);
}

// ======================= CSR build =======================
__global__ __launch_bounds__(256) void k_zero_i(int* __restrict__ p, int n) {
    int t = blockIdx.x * 256 + threadIdx.x;
    if (t < n) p[t] = 0;
}

__global__ __launch_bounds__(256) void k_hist(const int* __restrict__ dst,
                                              int* __restrict__ cnt, int nE) {
    int t = blockIdx.x * 256 + threadIdx.x;
    if (t < nE) atomicAdd(&cnt[dst[t]], 1);
}

__global__ __launch_bounds__(256) void k_scan1(const int* __restrict__ cnt, int n,
                                               int* __restrict__ bsum) {
    __shared__ int sh[256];
    int base = blockIdx.x * SCAN_TILE + threadIdx.x * 4;
    int s = 0;
#pragma unroll
    for (int i = 0; i < 4; ++i) { int idx = base + i; if (idx < n) s += cnt[idx]; }
    sh[threadIdx.x] = s;
    __syncthreads();
    for (int off = 128; off > 0; off >>= 1) {
        if (threadIdx.x < off) sh[threadIdx.x] += sh[threadIdx.x + off];
        __syncthreads();
    }
    if (threadIdx.x == 0) bsum[blockIdx.x] = sh[0];
}

__global__ __launch_bounds__(512) void k_scan2(int* __restrict__ bsum, int nb) {
    __shared__ int sh[512];
    int t = threadIdx.x;
    int v = (t < nb) ? bsum[t] : 0;
    sh[t] = v;
    __syncthreads();
    for (int off = 1; off < 512; off <<= 1) {
        int add = (t >= off) ? sh[t - off] : 0;
        __syncthreads();
        sh[t] += add;
        __syncthreads();
    }
    if (t < nb) bsum[t] = sh[t] - v;
}

__global__ __launch_bounds__(256) void k_scan3(const int* __restrict__ cnt, int n,
                                               const int* __restrict__ bsum,
                                               int* __restrict__ rowptr,
                                               int* __restrict__ cur) {
    __shared__ int sh[256];
    int base = blockIdx.x * SCAN_TILE + threadIdx.x * 4;
    int c[4]; int s = 0;
#pragma unroll
    for (int i = 0; i < 4; ++i) { int idx = base + i; c[i] = (idx < n) ? cnt[idx] : 0; s += c[i]; }
    sh[threadIdx.x] = s;
    __syncthreads();
    int v = s;
    for (int off = 1; off < 256; off <<= 1) {
        int add = (threadIdx.x >= off) ? sh[threadIdx.x - off] : 0;
        __syncthreads();
        sh[threadIdx.x] += add;
        __syncthreads();
    }
    int excl = sh[threadIdx.x] - v + bsum[blockIdx.x];
#pragma unroll
    for (int i = 0; i < 4; ++i) {
        int idx = base + i;
        if (idx < n) {
            rowptr[idx] = excl; cur[idx] = excl; excl += c[i];
            if (idx == n - 1) rowptr[n] = excl;
        }
    }
}

// permuted edge records: {src, ea_bits} — one 8B slot per edge
__global__ __launch_bounds__(256) void k_fill2(const int* __restrict__ src,
                                               const int* __restrict__ dst,
                                               const float* __restrict__ ea,
                                               int* __restrict__ cur,
                                               int2* __restrict__ pe, int nE) {
    int t = blockIdx.x * 256 + threadIdx.x;
    if (t >= nE) return;
    int d = dst[t];
    int slot = atomicAdd(&cur[d], 1);
    int2 r; r.x = src[t]; r.y = __float_as_int(ea[t]);
    pe[slot] = r;
}

// ======================= weight packing (MFMA fragment order) =======================
// Bp[((ks*8+ct)*64+lane)*8+j] = W[k=ks*32+(lane>>4)*8+j][col=ct*16+(lane&15)]
__global__ __launch_bounds__(256) void k_pack_fp(const float* __restrict__ W_fp,
                                                 unsigned short* __restrict__ Bp) {
    int t = blockIdx.x * 256 + threadIdx.x;       // 3*8*64*8 = 12288
    int j = t & 7, lane = (t >> 3) & 63, ct = (t >> 9) & 7, ks = t >> 12;
    int k = ks * 32 + ((lane >> 4) & 3) * 8 + j;  // 0..95
    int col = ct * 16 + (lane & 15);
    Bp[t] = f2bf(W_fp[k * 128 + col]);
}

// K=256: rows 0..127 = W_rt, 128..255 = W_pp
__global__ __launch_bounds__(256) void k_pack_fin(const float* __restrict__ W_rt,
                                                  const float* __restrict__ W_pp,
                                                  unsigned short* __restrict__ Bp) {
    int t = blockIdx.x * 256 + threadIdx.x;       // 8*8*64*8 = 32768
    int j = t & 7, lane = (t >> 3) & 63, ct = (t >> 9) & 7, ks = t >> 12;
    int k = ks * 32 + ((lane >> 4) & 3) * 8 + j;  // 0..255
    int col = ct * 16 + (lane & 15);
    float v = (k < 128) ? W_rt[k * 128 + col] : W_pp[(k - 128) * 128 + col];
    Bp[t] = f2bf(v);
}

// ======================= gathers =======================
// cells->faces on RAW x_centers (8 f32 cols, 32B rows): thread per face
__global__ __launch_bounds__(256) void k_gather8(const float* __restrict__ xc,
                                                 const int* __restrict__ ptr,
                                                 const int2* __restrict__ pe,
                                                 float* __restrict__ aggc, int nRows) {
    int r = blockIdx.x * 256 + threadIdx.x;
    if (r >= nRows) return;
    int e = ptr[r], end = ptr[r + 1];
    float a[8] = {};
    for (; e + 1 < end; e += 2) {
        int2 q0 = pe[e], q1 = pe[e + 1];
        float w0 = __int_as_float(q0.y), w1 = __int_as_float(q1.y);
        const float* p0 = xc + (size_t)q0.x * 8;
        const float* p1 = xc + (size_t)q1.x * 8;
        float4 u0 = *(const float4*)p0, u1 = *(const float4*)(p0 + 4);
        float4 v0 = *(const float4*)p1, v1 = *(const float4*)(p1 + 4);
        a[0] += w0 * u0.x + w1 * v0.x; a[1] += w0 * u0.y + w1 * v0.y;
        a[2] += w0 * u0.z + w1 * v0.z; a[3] += w0 * u0.w + w1 * v0.w;
        a[4] += w0 * u1.x + w1 * v1.x; a[5] += w0 * u1.y + w1 * v1.y;
        a[6] += w0 * u1.z + w1 * v1.z; a[7] += w0 * u1.w + w1 * v1.w;
    }
    if (e < end) {
        int2 q0 = pe[e];
        float w0 = __int_as_float(q0.y);
        const float* p0 = xc + (size_t)q0.x * 8;
        float4 u0 = *(const float4*)p0, u1 = *(const float4*)(p0 + 4);
        a[0] += w0 * u0.x; a[1] += w0 * u0.y; a[2] += w0 * u0.z; a[3] += w0 * u0.w;
        a[4] += w0 * u1.x; a[5] += w0 * u1.y; a[6] += w0 * u1.z; a[7] += w0 * u1.w;
    }
    float4* o = (float4*)(aggc + (size_t)r * 8);
    o[0] = make_float4(a[0], a[1], a[2], a[3]);
    o[1] = make_float4(a[4], a[5], a[6], a[7]);
}

// dense: yfp = bf16([aggc @ W_cf + b_cf | x_face]); 24 threads per face row
__global__ __launch_bounds__(256) void k_face_tf(const float* __restrict__ aggc,
                                                 const float* __restrict__ x_face,
                                                 const float* __restrict__ W,
                                                 const float* __restrict__ b,
                                                 unsigned short* __restrict__ yfp) {
    __shared__ float Ws[512];
    __shared__ float bs[64];
    for (int i = threadIdx.x; i < 512; i += 256) Ws[i] = W[i];
    if (threadIdx.x < 64) bs[threadIdx.x] = b[threadIdx.x];
    __syncthreads();
    int t = blockIdx.x * 256 + threadIdx.x;
    int row = t / 24, c = t - row * 24;
    if (row >= N_FACES) return;
    if (c < 16) {
        int j = c * 4;
        float a0 = bs[j], a1 = bs[j + 1], a2 = bs[j + 2], a3 = bs[j + 3];
        const float* ar = aggc + (size_t)row * 8;
#pragma unroll
        for (int k = 0; k < 8; ++k) {
            float x = ar[k];
            const float* wr = Ws + k * 64 + j;
            a0 += x * wr[0]; a1 += x * wr[1]; a2 += x * wr[2]; a3 += x * wr[3];
        }
        ushort4 o; o.x = f2bf(a0); o.y = f2bf(a1); o.z = f2bf(a2); o.w = f2bf(a3);
        *(ushort4*)(yfp + (size_t)row * 96 + j) = o;
    } else {
        int col = c - 16;
        yfp[(size_t)row * 96 + 64 + col] = f2bf(x_face[(size_t)row * 8 + col]);
    }
}

// faces->points on yfp (96 bf16 cols): 2 rows per wave, 32 lanes x 3 cols
__global__ __launch_bounds__(256) void k_gather96(const unsigned short* __restrict__ feat,
                                                  const int* __restrict__ ptr,
                                                  const int2* __restrict__ pe,
                                                  unsigned short* __restrict__ aggf, int nRows) {
    int gw = (blockIdx.x * 256 + threadIdx.x) >> 6;
    int lane = threadIdx.x & 63;
    int row = gw * 2 + (lane >> 5);
    int l = lane & 31;
    if (row >= nRows) return;
    int e = ptr[row], end = ptr[row + 1];
    float a0 = 0.f, a1 = 0.f, a2 = 0.f;
    for (; e + 1 < end; e += 2) {
        int2 q0 = pe[e], q1 = pe[e + 1];
        float w0 = __int_as_float(q0.y), w1 = __int_as_float(q1.y);
        const unsigned short* f0 = feat + (size_t)q0.x * 96 + l;
        const unsigned short* f1 = feat + (size_t)q1.x * 96 + l;
        unsigned short x0 = f0[0], x1 = f0[32], x2 = f0[64];
        unsigned short y0 = f1[0], y1 = f1[32], y2 = f1[64];
        a0 += w0 * bf2f(x0) + w1 * bf2f(y0);
        a1 += w0 * bf2f(x1) + w1 * bf2f(y1);
        a2 += w0 * bf2f(x2) + w1 * bf2f(y2);
    }
    if (e < end) {
        int2 q0 = pe[e];
        float w0 = __int_as_float(q0.y);
        const unsigned short* f0 = feat + (size_t)q0.x * 96 + l;
        a0 += w0 * bf2f(f0[0]); a1 += w0 * bf2f(f0[32]); a2 += w0 * bf2f(f0[64]);
    }
    unsigned short* o = aggf + (size_t)row * 96 + l;
    o[0] = f2bf(a0); o[32] = f2bf(a1); o[64] = f2bf(a2);
}

// points->points on y_ptb (128 bf16 cols): 2 rows per wave, 32 lanes x 4 cols
__global__ __launch_bounds__(256) void k_gather128pp(const unsigned short* __restrict__ feat,
                                                     const int* __restrict__ ptr,
                                                     const int2* __restrict__ pe,
                                                     unsigned short* __restrict__ aggp, int nRows) {
    int gw = (blockIdx.x * 256 + threadIdx.x) >> 6;
    int lane = threadIdx.x & 63;
    int row = gw * 2 + (lane >> 5);
    int l = lane & 31;
    if (row >= nRows) return;
    int e = ptr[row], end = ptr[row + 1];
    float a0 = 0.f, a1 = 0.f, a2 = 0.f, a3 = 0.f;
    for (; e + 1 < end; e += 2) {
        int2 q0 = pe[e], q1 = pe[e + 1];
        float w0 = __int_as_float(q0.y), w1 = __int_as_float(q1.y);
        const unsigned short* f0 = feat + ((size_t)q0.x << 7) + l;
        const unsigned short* f1 = feat + ((size_t)q1.x << 7) + l;
        unsigned short x0 = f0[0], x1 = f0[32], x2 = f0[64], x3 = f0[96];
        unsigned short y0 = f1[0], y1 = f1[32], y2 = f1[64], y3 = f1[96];
        a0 += w0 * bf2f(x0) + w1 * bf2f(y0);
        a1 += w0 * bf2f(x1) + w1 * bf2f(y1);
        a2 += w0 * bf2f(x2) + w1 * bf2f(y2);
        a3 += w0 * bf2f(x3) + w1 * bf2f(y3);
    }
    if (e < end) {
        int2 q0 = pe[e];
        float w0 = __int_as_float(q0.y);
        const unsigned short* f0 = feat + ((size_t)q0.x << 7) + l;
        a0 += w0 * bf2f(f0[0]);  a1 += w0 * bf2f(f0[32]);
        a2 += w0 * bf2f(f0[64]); a3 += w0 * bf2f(f0[96]);
    }
    unsigned short* o = aggp + ((size_t)row << 7) + l;
    o[0] = f2bf(a0); o[32] = f2bf(a1); o[64] = f2bf(a2); o[96] = f2bf(a3);
}

// ======================= MFMA stages =======================
// y_ptb = bf16(aggf[200k,96] @ W_fp + b_fp)
__global__ __launch_bounds__(256) void k_mfma96(const unsigned short* __restrict__ A,
                                                const unsigned short* __restrict__ Bp,
                                                const float* __restrict__ bias,
                                                unsigned short* __restrict__ O) {
    const int w = threadIdx.x >> 6;
    const int lane = threadIdx.x & 63;
    const int rg = w >> 1, cg = w & 1;
    const int row0 = blockIdx.x * 32 + rg * 16;
    bf16x8 bfr[3][4];
#pragma unroll
    for (int ks = 0; ks < 3; ++ks)
#pragma unroll
        for (int c = 0; c < 4; ++c) {
            int ct = cg * 4 + c;
            bfr[ks][c] = *(const bf16x8*)(Bp + ((size_t)(ks * 8 + ct) * 64 + lane) * 8);
        }
    f32x4 acc[4] = {};
    const unsigned short* arow = A + (size_t)(row0 + (lane & 15)) * 96 + ((lane >> 4) * 8);
#pragma unroll
    for (int ks = 0; ks < 3; ++ks) {
        bf16x8 af = *(const bf16x8*)(arow + ks * 32);
#pragma unroll
        for (int c = 0; c < 4; ++c)
            acc[c] = __builtin_amdgcn_mfma_f32_16x16x32_bf16(af, bfr[ks][c], acc[c], 0, 0, 0);
    }
    const int rbase = row0 + (lane >> 4) * 4;
#pragma unroll
    for (int c = 0; c < 4; ++c) {
        int gcol = cg * 64 + c * 16 + (lane & 15);
        float bv = bias[gcol];
#pragma unroll
        for (int r = 0; r < 4; ++r)
            O[(size_t)(rbase + r) * 128 + gcol] = f2bf(acc[c][r] + bv);
    }
}

// out = [y_ptb | aggp] @ [W_rt;W_pp] + b_pp (K=256, f32 out)
__global__ __launch_bounds__(256) void k_mfma_fin(const unsigned short* __restrict__ A1,
                                                  const unsigned short* __restrict__ A2,
                                                  const unsigned short* __restrict__ Bp,
                                                  const float* __restrict__ bias,
                                                  float* __restrict__ out) {
    const int w = threadIdx.x >> 6;
    const int lane = threadIdx.x & 63;
    const int rg = w >> 1, cg = w & 1;
    const int row0 = blockIdx.x * 32 + rg * 16;
    bf16x8 bfr[8][4];
#pragma unroll
    for (int ks = 0; ks < 8; ++ks)
#pragma unroll
        for (int c = 0; c < 4; ++c) {
            int ct = cg * 4 + c;
            bfr[ks][c] = *(const bf16x8*)(Bp + ((size_t)(ks * 8 + ct) * 64 + lane) * 8);
        }
    f32x4 acc[4] = {};
    const unsigned short* a1 = A1 + (size_t)(row0 + (lane & 15)) * 128 + ((lane >> 4) * 8);
    const unsigned short* a2 = A2 + (size_t)(row0 + (lane & 15)) * 128 + ((lane >> 4) * 8);
#pragma unroll
    for (int ks = 0; ks < 4; ++ks) {
        bf16x8 af = *(const bf16x8*)(a1 + ks * 32);
#pragma unroll
        for (int c = 0; c < 4; ++c)
            acc[c] = __builtin_amdgcn_mfma_f32_16x16x32_bf16(af, bfr[ks][c], acc[c], 0, 0, 0);
    }
#pragma unroll
    for (int ks = 0; ks < 4; ++ks) {
        bf16x8 af = *(const bf16x8*)(a2 + ks * 32);
#pragma unroll
        for (int c = 0; c < 4; ++c)
            acc[c] = __builtin_amdgcn_mfma_f32_16x16x32_bf16(af, bfr[ks + 4][c], acc[c], 0, 0, 0);
    }
    const int rbase = row0 + (lane >> 4) * 4;
#pragma unroll
    for (int c = 0; c < 4; ++c) {
        int gcol = cg * 64 + c * 16 + (lane & 15);
        float bv = bias[gcol];
#pragma unroll
        for (int r = 0; r < 4; ++r)
            out[(size_t)(rbase + r) * 128 + gcol] = acc[c][r] + bv;
    }
}

extern "C" void kernel_launch(void* const* d_in, const int* in_sizes, int n_in,
                              void* d_out, int out_size, void* d_ws, size_t ws_size,
                              hipStream_t stream) {
    const float* x_centers = (const float*)d_in[0];
    const float* x_face    = (const float*)d_in[1];
    const float* W_cf      = (const float*)d_in[2];
    const float* b_cf      = (const float*)d_in[3];
    const float* W_fp      = (const float*)d_in[4];
    const float* b_fp      = (const float*)d_in[5];
    const float* W_pp      = (const float*)d_in[6];
    const float* W_rt      = (const float*)d_in[7];
    const float* b_pp      = (const float*)d_in[8];
    const float* ea_cf     = (const float*)d_in[9];
    const float* ea_fp     = (const float*)d_in[10];
    const float* ea_pp     = (const float*)d_in[11];
    const int* src_cf      = (const int*)d_in[12];
    const int* dst_cf      = (const int*)d_in[13];
    const int* src_fp      = (const int*)d_in[14];
    const int* dst_fp      = (const int*)d_in[15];
    const int* src_pp      = (const int*)d_in[16];
    const int* dst_pp      = (const int*)d_in[17];
    float* out = (float*)d_out;

    char* ws = (char*)d_ws;
    unsigned short* yfp   = (unsigned short*)(ws + 0);           // bf16 [400k][96]  76.8MB
    unsigned short* aggf  = (unsigned short*)(ws + 80000000);    // bf16 [200k][96]  38.4MB
    unsigned short* y_ptb = (unsigned short*)(ws + 120000000);   // bf16 [200k][128] 51.2MB
    unsigned short* aggp  = (unsigned short*)(ws + 172000000);   // bf16 [200k][128] 51.2MB
    float* aggc           = (float*)(ws + 224000000);            // f32  [400k][8]   12.8MB
    int2*  pe_cf  = (int2*)(ws + 237000000);                     // 6.4MB
    int2*  pe_fp  = (int2*)(ws + 244000000);                     // 6.4MB
    int2*  pe_pp  = (int2*)(ws + 251000000);                     // 9.6MB
    int*   cf_ptr = (int*)(ws + 261000000);
    int*   cf_cur = (int*)(ws + 263000000);
    int*   fp_ptr = (int*)(ws + 265000000);
    int*   fp_cur = (int*)(ws + 266000000);
    int*   pp_ptr = (int*)(ws + 267000000);
    int*   pp_cur = (int*)(ws + 268000000);
    int*   bsum1  = (int*)(ws + 269000000);
    int*   bsum2  = (int*)(ws + 269010000);
    unsigned short* Bp_fp  = (unsigned short*)(ws + 269020000);  // 24KB
    unsigned short* Bp_fin = (unsigned short*)(ws + 269050000);  // 64KB

    // ---- weight packing ----
    k_pack_fp<<<48, 256, 0, stream>>>(W_fp, Bp_fp);
    k_pack_fin<<<128, 256, 0, stream>>>(W_rt, W_pp, Bp_fin);
    // ---- CSR cf ----
    k_zero_i<<<1563, 256, 0, stream>>>(cf_cur, N_FACES);
    k_hist<<<3125, 256, 0, stream>>>(dst_cf, cf_cur, E_CF);
    k_scan1<<<391, 256, 0, stream>>>(cf_cur, N_FACES, bsum1);
    k_scan2<<<1, 512, 0, stream>>>(bsum1, 391);
    k_scan3<<<391, 256, 0, stream>>>(cf_cur, N_FACES, bsum1, cf_ptr, cf_cur);
    k_fill2<<<3125, 256, 0, stream>>>(src_cf, dst_cf, ea_cf, cf_cur, pe_cf, E_CF);
    // ---- CSR fp ----
    k_zero_i<<<782, 256, 0, stream>>>(fp_cur, N_POINTS);
    k_hist<<<3125, 256, 0, stream>>>(dst_fp, fp_cur, E_FP);
    k_scan1<<<196, 256, 0, stream>>>(fp_cur, N_POINTS, bsum2);
    k_scan2<<<1, 512, 0, stream>>>(bsum2, 196);
    k_scan3<<<196, 256, 0, stream>>>(fp_cur, N_POINTS, bsum2, fp_ptr, fp_cur);
    k_fill2<<<3125, 256, 0, stream>>>(src_fp, dst_fp, ea_fp, fp_cur, pe_fp, E_FP);
    // ---- CSR pp ----
    k_zero_i<<<782, 256, 0, stream>>>(pp_cur, N_POINTS);
    k_hist<<<4688, 256, 0, stream>>>(dst_pp, pp_cur, E_PP);
    k_scan1<<<196, 256, 0, stream>>>(pp_cur, N_POINTS, bsum2);
    k_scan2<<<1, 512, 0, stream>>>(bsum2, 196);
    k_scan3<<<196, 256, 0, stream>>>(pp_cur, N_POINTS, bsum2, pp_ptr, pp_cur);
    k_fill2<<<4688, 256, 0, stream>>>(src_pp, dst_pp, ea_pp, pp_cur, pe_pp, E_PP);
    // ---- pipeline ----
    k_gather8<<<1563, 256, 0, stream>>>(x_centers, cf_ptr, pe_cf, aggc, N_FACES);
    k_face_tf<<<37500, 256, 0, stream>>>(aggc, x_face, W_cf, b_cf, yfp);
    k_gather96<<<25000, 256, 0, stream>>>(yfp, fp_ptr, pe_fp, aggf, N_POINTS);
    k_mfma96<<<6250, 256, 0, stream>>>(aggf, Bp_fp, b_fp, y_ptb);
    k_gather128pp<<<25000, 256, 0, stream>>>(y_ptb, pp_ptr, pe_pp, aggp, N_POINTS);
    k_mfma_fin<<<6250, 256, 0, stream>>>(y_ptb, aggp, Bp_fin, b_pp, out);
}